// Round 1
// baseline (399.164 us; speedup 1.0000x reference)
//
#include <hip/hip_runtime.h>

#define BSZ 64
#define SEQ 512
#define HID 768
#define NK  21

// ---------------- GEMM + bias: logits = hidden @ W + b ----------------
// grid 2688 x 256 threads; one thread per output element (r,k).
__global__ __launch_bounds__(256) void gemm_bias_kernel(
    const float* __restrict__ hidden, const float* __restrict__ W,
    const float* __restrict__ bias, float* __restrict__ out)
{
    __shared__ float wl[HID * NK];           // 64.5 KB
    const int tid = threadIdx.x;
    for (int idx = tid; idx < HID * NK; idx += 256) wl[idx] = W[idx];
    __syncthreads();

    const int g = blockIdx.x * 256 + tid;    // 0 .. 688127
    const int r = g / NK;                    // row (compiler magic-div)
    const int k = g - r * NK;                // class

    const float4* hp = (const float4*)(hidden + (long)r * HID);
    float acc = 0.f;
    #pragma unroll 8
    for (int j = 0; j < HID / 4; ++j) {
        float4 h = hp[j];
        int base = (4 * j) * NK + k;
        acc = fmaf(h.x, wl[base          ], acc);
        acc = fmaf(h.y, wl[base +     NK ], acc);
        acc = fmaf(h.z, wl[base + 2 * NK ], acc);
        acc = fmaf(h.w, wl[base + 3 * NK ], acc);
    }
    out[g] = acc + bias[k];
}

// ---------------- CRF: one wave per batch ----------------
__global__ __launch_bounds__(64) void crf_kernel(
    const float* __restrict__ logits,
    const float* __restrict__ start_t,
    const float* __restrict__ trans,
    const float* __restrict__ end_t,
    const int* __restrict__ labels,
    const int* __restrict__ mask,
    float* __restrict__ per_batch)
{
    __shared__ float lg[SEQ * NK];           // 43 KB: this batch's logits
    const int b    = blockIdx.x;
    const int lane = threadIdx.x;

    // stage logits block into LDS (coalesced float4)
    {
        const float4* g4 = (const float4*)(logits + (long)b * SEQ * NK);
        float4* l4 = (float4*)lg;
        for (int idx = lane; idx < SEQ * NK / 4; idx += 64) l4[idx] = g4[idx];
    }

    const int* lab = labels + b * SEQ;
    const int* msk = mask   + b * SEQ;

    // sequence length (mask is a prefix of ones)
    int cnt = 0;
    for (int t = lane; t < SEQ; t += 64) cnt += (msk[t] != 0);
    #pragma unroll
    for (int off = 32; off > 0; off >>= 1) cnt += __shfl_xor(cnt, off, 64);
    const int L = cnt;

    __syncthreads();   // LDS staging visible

    // ---- numerator (gold-path score), wave-parallel over t ----
    float numacc = 0.f;
    for (int t = lane; t < L; t += 64) {
        if (t == 0) numacc += start_t[lab[0]] + lg[lab[0]];
        else        numacc += lg[t * NK + lab[t]] + trans[lab[t - 1] * NK + lab[t]];
    }
    if (lane == 0) numacc += end_t[lab[L - 1]];
    #pragma unroll
    for (int off = 32; off > 0; off >>= 1) numacc += __shfl_xor(numacc, off, 64);
    const float num = numacc;

    // ---- forward scan: alpha'_j = m + log(sum_i exp(alpha_i - m) * E_ij) + emit_j ----
    const int j = (lane < NK) ? lane : 0;
    float Ecol[NK];                          // E[i][j] = exp(trans[i][j]), column for this lane
    #pragma unroll
    for (int i = 0; i < NK; ++i) Ecol[i] = __expf(trans[i * NK + j]);

    float alpha = (lane < NK) ? (start_t[j] + lg[lane]) : -1e30f;

    for (int t = 1; t < L; ++t) {
        const float emit = lg[t * NK + j];
        // representative offset: exact algebra for any m; lane-0 alpha keeps exp in range
        const float m = __shfl(alpha, 0, 64);
        const float e = __expf(alpha - m);   // lanes >= NK -> exp(-1e30) = 0
        float s0 = 0.f, s1 = 0.f, s2 = 0.f;
        #pragma unroll
        for (int i = 0; i < NK; i += 3) {
            s0 = fmaf(Ecol[i    ], __shfl(e, i,     64), s0);
            s1 = fmaf(Ecol[i + 1], __shfl(e, i + 1, 64), s1);
            s2 = fmaf(Ecol[i + 2], __shfl(e, i + 2, 64), s2);
        }
        const float na = m + __logf((s0 + s1) + s2) + emit;
        alpha = (lane < NK) ? na : -1e30f;
    }

    // ---- logZ = logsumexp_j(alpha_j + end_t[j]) ----
    const float v  = (lane < NK) ? (alpha + end_t[j]) : -1e30f;
    const float m2 = __shfl(v, 0, 64);
    float ee = (lane < NK) ? __expf(v - m2) : 0.f;
    #pragma unroll
    for (int off = 32; off > 0; off >>= 1) ee += __shfl_xor(ee, off, 64);

    if (lane == 0) per_batch[b] = m2 + __logf(ee) - num;
}

// ---------------- final reduce: nll = sum_b (logZ_b - num_b) ----------------
__global__ __launch_bounds__(64) void reduce_kernel(
    const float* __restrict__ pb, float* __restrict__ out)
{
    float v = pb[threadIdx.x];
    #pragma unroll
    for (int off = 32; off > 0; off >>= 1) v += __shfl_xor(v, off, 64);
    if (threadIdx.x == 0) out[BSZ * SEQ * NK] = v;
}

extern "C" void kernel_launch(void* const* d_in, const int* in_sizes, int n_in,
                              void* d_out, int out_size, void* d_ws, size_t ws_size,
                              hipStream_t stream)
{
    const float* hidden  = (const float*)d_in[0];
    const float* W       = (const float*)d_in[1];
    const float* bias    = (const float*)d_in[2];
    const float* start_t = (const float*)d_in[3];
    const float* trans   = (const float*)d_in[4];
    const float* end_t   = (const float*)d_in[5];
    const int*   labels  = (const int*)d_in[6];
    const int*   mask    = (const int*)d_in[7];
    float* out = (float*)d_out;
    float* pb  = (float*)d_ws;

    gemm_bias_kernel<<<(BSZ * SEQ * NK) / 256, 256, 0, stream>>>(hidden, W, bias, out);
    crf_kernel<<<BSZ, 64, 0, stream>>>(out, start_t, trans, end_t, labels, mask, pb);
    reduce_kernel<<<1, 64, 0, stream>>>(pb, out);
}